// Round 7
// baseline (108.293 us; speedup 1.0000x reference)
//
#include <hip/hip_runtime.h>
#include <hip/hip_cooperative_groups.h>

#define NB 8
#define NO 2048
#define NQ 2048
#define ND 128
#define R  12        // Taylor terms for exp(x), x = tq*to/sigma^2 in [0,1] -> err ~ 6e-9

namespace cg = cooperative_groups;

// Single fused kernel, cooperative launch, one grid sync.
// grid 256 = 8 b x 32 sub; block 512.
// P1: moments for o-chunk `sub` -> Mpart[b][sub][12][128], spart[b][sub][12]
// sync
// P2: per-block redundant batch reduce (local-L2) + W-fold -> P[12][128] in LDS
// P3: emit q-tile `sub` (64 q rows)
__global__ __launch_bounds__(512, 1) void fused_kernel(
    const float* __restrict__ obs_emb, const float* __restrict__ obs_times,
    const float* __restrict__ query_times, const float* __restrict__ obs_mask,
    const float* __restrict__ log_sigma, const float* __restrict__ W_proj,
    const float* __restrict__ b_proj, float* __restrict__ Mpart,
    float* __restrict__ spart, float* __restrict__ out)
{
  __shared__ __align__(16) float smem[6144];  // 24 KB: P1 Lacc[4][12][128]; P2 Ml[1536] + Pl@2048[8*196]
  __shared__ float Ls[4][R];
  __shared__ float slb[R];

  const int tid = threadIdx.x;
  const int b   = blockIdx.x & 7;             // XCD-aligned batch
  const int sub = blockIdx.x >> 3;            // 0..31: o-chunk (P1) / q-tile (P3)

  const float ls     = log_sigma[0];
  const float inv_s2 = __expf(-2.0f * ls);    // 1/sigma^2
  const float kp     = 0.5f * inv_s2;

  // ---------------- phase 1: moment chunk ----------------
  {
    const int d    = tid & 127;
    const int osub = tid >> 7;                // 0..3, 16 o's each
    const int o0   = sub * 64 + osub * 16;

    float ev[16], tof[16], mkf[16];
    #pragma unroll
    for (int i = 0; i < 16; ++i) {
      tof[i] = obs_times[b * NO + o0 + i];    // wave-uniform
      mkf[i] = obs_mask[b * NO + o0 + i];
      ev[i]  = obs_emb[((size_t)(b * NO + o0 + i)) * ND + d];
    }
    const float inv_np1[R] = {1.f, 0.5f, 1.f/3.f, 0.25f, 0.2f, 1.f/6.f,
                              1.f/7.f, 0.125f, 1.f/9.f, 0.1f, 1.f/11.f, 1.f/12.f};
    float acc[R], sl[R];
    #pragma unroll
    for (int n = 0; n < R; ++n) { acc[n] = 0.f; sl[n] = 0.f; }
    #pragma unroll
    for (int i = 0; i < 16; ++i) {
      const float u = tof[i] * inv_s2;
      float c = mkf[i] * __expf(-kp * tof[i] * tof[i]);
      #pragma unroll
      for (int n = 0; n < R; ++n) {
        acc[n] = fmaf(c, ev[i], acc[n]);
        sl[n] += c;
        c *= u * inv_np1[n];
      }
    }
    #pragma unroll
    for (int n = 0; n < R; ++n) smem[(osub * R + n) * ND + d] = acc[n];
    if (d == 0) {
      #pragma unroll
      for (int n = 0; n < R; ++n) Ls[osub][n] = sl[n];
    }
    __syncthreads();
    float* Mout = Mpart + ((size_t)(b * 32 + sub)) * (R * ND);
    #pragma unroll
    for (int k = 0; k < 3; ++k) {
      const int e = k * 512 + tid;            // flat n*128+d
      Mout[e] = (smem[e] + smem[1536 + e]) + (smem[3072 + e] + smem[4608 + e]);
    }
    if (tid < R)
      spart[(b * 32 + sub) * R + tid] =
          (Ls[0][tid] + Ls[1][tid]) + (Ls[2][tid] + Ls[3][tid]);
  }

  __threadfence();                            // device-scope release (cross-XCD via L3)
  cg::this_grid().sync();

  // ---------------- phase 2: batch reduce + W fold ----------------
  {
    const float* Mp = Mpart + (size_t)b * 32 * (R * ND);
    float vout[3];
    #pragma unroll
    for (int k = 0; k < 3; ++k) {
      const int e = k * 512 + tid;
      float v0 = 0.f, v1 = 0.f, v2 = 0.f, v3 = 0.f;
      #pragma unroll
      for (int ch = 0; ch < 32; ch += 4) {
        v0 += Mp[(ch + 0) * (R * ND) + e];
        v1 += Mp[(ch + 1) * (R * ND) + e];
        v2 += Mp[(ch + 2) * (R * ND) + e];
        v3 += Mp[(ch + 3) * (R * ND) + e];
      }
      vout[k] = (v0 + v1) + (v2 + v3);
    }
    float sv = 0.f;
    if (tid < R) {
      const float* sp = spart + b * 32 * R;
      #pragma unroll
      for (int ch = 0; ch < 32; ++ch) sv += sp[ch * R + tid];
    }
    __syncthreads();                          // P1 smem fully consumed grid-wide (sync above)
    #pragma unroll
    for (int k = 0; k < 3; ++k) smem[k * 512 + tid] = vout[k];  // Ml
    if (tid < R) slb[tid] = sv;
    __syncthreads();

    // P = M @ W^T  (thread: e = tid>>2, 3 n's at nh=(tid&3)*3); Pl at smem+2048, [eh][n][16] stride 196
    const int e  = tid >> 2;
    const int nh = (tid & 3) * 3;
    const float4* Wr = reinterpret_cast<const float4*>(W_proj) + e * 32;
    const float4* M4 = reinterpret_cast<const float4*>(smem);
    float p0 = 0.f, p1 = 0.f, p2 = 0.f;
    #pragma unroll 8
    for (int d4 = 0; d4 < 32; ++d4) {
      const float4 w  = Wr[d4];
      const float4 m0 = M4[(nh + 0) * 32 + d4];
      const float4 m1 = M4[(nh + 1) * 32 + d4];
      const float4 m2 = M4[(nh + 2) * 32 + d4];
      p0 = fmaf(w.x, m0.x, fmaf(w.y, m0.y, fmaf(w.z, m0.z, fmaf(w.w, m0.w, p0))));
      p1 = fmaf(w.x, m1.x, fmaf(w.y, m1.y, fmaf(w.z, m1.z, fmaf(w.w, m1.w, p1))));
      p2 = fmaf(w.x, m2.x, fmaf(w.y, m2.y, fmaf(w.z, m2.z, fmaf(w.w, m2.w, p2))));
    }
    float* Pl = smem + 2048;
    Pl[(e >> 4) * 196 + (nh + 0) * 16 + (e & 15)] = p0;
    Pl[(e >> 4) * 196 + (nh + 1) * 16 + (e & 15)] = p1;
    Pl[(e >> 4) * 196 + (nh + 2) * 16 + (e & 15)] = p2;
    __syncthreads();
  }

  // ---------------- phase 3: emit q-tile ----------------
  {
    const float* Pl = smem + 2048;
    const int q  = sub * 64 + (tid >> 3);
    const int eh = tid & 7;                   // e-range [eh*16, +16)
    const float tq = query_times[b * NQ + q];

    float c[R];
    c[0] = 1.f;
    #pragma unroll
    for (int n = 1; n < R; ++n) c[n] = c[n - 1] * tq;
    float wsum = 0.f;
    #pragma unroll
    for (int n = 0; n < R; ++n) wsum = fmaf(c[n], slb[n], wsum);
    const float inv = 1.0f / fmaxf(wsum, 1e-8f);

    const float* Pe = Pl + eh * 196;
    float4 a0 = {0,0,0,0}, a1 = {0,0,0,0}, a2 = {0,0,0,0}, a3 = {0,0,0,0};
    #pragma unroll
    for (int n = 0; n < R; ++n) {
      const float cn = c[n];
      const float4 p0 = *reinterpret_cast<const float4*>(Pe + n * 16 + 0);
      const float4 p1 = *reinterpret_cast<const float4*>(Pe + n * 16 + 4);
      const float4 p2 = *reinterpret_cast<const float4*>(Pe + n * 16 + 8);
      const float4 p3 = *reinterpret_cast<const float4*>(Pe + n * 16 + 12);
      a0.x = fmaf(cn, p0.x, a0.x); a0.y = fmaf(cn, p0.y, a0.y);
      a0.z = fmaf(cn, p0.z, a0.z); a0.w = fmaf(cn, p0.w, a0.w);
      a1.x = fmaf(cn, p1.x, a1.x); a1.y = fmaf(cn, p1.y, a1.y);
      a1.z = fmaf(cn, p1.z, a1.z); a1.w = fmaf(cn, p1.w, a1.w);
      a2.x = fmaf(cn, p2.x, a2.x); a2.y = fmaf(cn, p2.y, a2.y);
      a2.z = fmaf(cn, p2.z, a2.z); a2.w = fmaf(cn, p2.w, a2.w);
      a3.x = fmaf(cn, p3.x, a3.x); a3.y = fmaf(cn, p3.y, a3.y);
      a3.z = fmaf(cn, p3.z, a3.z); a3.w = fmaf(cn, p3.w, a3.w);
    }
    const float4* B4 = reinterpret_cast<const float4*>(b_proj) + eh * 4;
    const float4 bb0 = B4[0], bb1 = B4[1], bb2 = B4[2], bb3 = B4[3];
    float4* orow = reinterpret_cast<float4*>(out + ((size_t)(b * NQ + q)) * ND + eh * 16);
    orow[0] = make_float4(fmaf(a0.x, inv, bb0.x), fmaf(a0.y, inv, bb0.y),
                          fmaf(a0.z, inv, bb0.z), fmaf(a0.w, inv, bb0.w));
    orow[1] = make_float4(fmaf(a1.x, inv, bb1.x), fmaf(a1.y, inv, bb1.y),
                          fmaf(a1.z, inv, bb1.z), fmaf(a1.w, inv, bb1.w));
    orow[2] = make_float4(fmaf(a2.x, inv, bb2.x), fmaf(a2.y, inv, bb2.y),
                          fmaf(a2.z, inv, bb2.z), fmaf(a2.w, inv, bb2.w));
    orow[3] = make_float4(fmaf(a3.x, inv, bb3.x), fmaf(a3.y, inv, bb3.y),
                          fmaf(a3.z, inv, bb3.z), fmaf(a3.w, inv, bb3.w));
  }
}

extern "C" void kernel_launch(void* const* d_in, const int* in_sizes, int n_in,
                              void* d_out, int out_size, void* d_ws, size_t ws_size,
                              hipStream_t stream) {
  const float* obs_emb     = (const float*)d_in[0];
  const float* obs_times   = (const float*)d_in[1];
  const float* query_times = (const float*)d_in[2];
  const float* obs_mask    = (const float*)d_in[3];
  const float* log_sigma   = (const float*)d_in[4];
  const float* W_proj      = (const float*)d_in[5];
  const float* b_proj      = (const float*)d_in[6];
  float* out = (float*)d_out;

  float* Mpart = (float*)d_ws;                          // 8*32*12*128 f32 = 1.57 MB
  float* spart = Mpart + (size_t)NB * 32 * R * ND;      // 8*32*12

  void* args[] = {
    (void*)&obs_emb, (void*)&obs_times, (void*)&query_times, (void*)&obs_mask,
    (void*)&log_sigma, (void*)&W_proj, (void*)&b_proj,
    (void*)&Mpart, (void*)&spart, (void*)&out
  };
  hipLaunchCooperativeKernel((void*)fused_kernel, dim3(NB * 32), dim3(512),
                             args, 0, stream);
}